// Round 5
// baseline (286.438 us; speedup 1.0000x reference)
//
#include <hip/hip_runtime.h>

// MultiHeadContrastive on MI355X (gfx950).
// prep (fused: zero + meta + weight-transpose + X->bf16) -> GEMM1 -> GEMM2
//   (normalize, scale by sqrt(5*log2e)) -> class sums -> fused NxN sim
//   (col tiles staged in LDS, raw v_exp_f32) -> finalize -> out.
// Z stored PRE-SCALED: zs = sqrt(5*log2e)*z so 2^(zs_i.zs_j) = exp(sim/tau).

typedef __attribute__((ext_vector_type(8))) short bs8;   // 8 x bf16
typedef __attribute__((ext_vector_type(4))) float f4;    // MFMA accumulator

#define MFMA_BF16(a, b, c) __builtin_amdgcn_mfma_f32_16x16x32_bf16((a), (b), (c), 0, 0, 0)

// raw v_exp_f32 — NEVER ocml exp2f (R4 post-mortem: +17us of VALU fixup code)
#if defined(__has_builtin)
#if __has_builtin(__builtin_amdgcn_exp2f)
#define EXP2F(x) __builtin_amdgcn_exp2f(x)
#endif
#endif
#ifndef EXP2F
__device__ __forceinline__ float __exp2_raw(float x) {
  float r;
  asm volatile("v_exp_f32 %0, %1" : "=v"(r) : "v"(x));
  return r;
}
#define EXP2F(x) __exp2_raw(x)
#endif

#define SQRT_KL2E 2.6857914f    // sqrt(5 * log2(e))
#define LN2F      0.6931471805599453f

__device__ __forceinline__ unsigned short f2bf(float f) {
  unsigned int u = __float_as_uint(f);
  u = (u + 0x7fffu + ((u >> 16) & 1u)) >> 16;   // RNE
  return (unsigned short)u;
}
__device__ __forceinline__ float bf2f(unsigned short s) {
  return __uint_as_float(((unsigned int)s) << 16);
}
// pack two f32 -> two bf16 (truncation) in ONE v_perm_b32 (verified R3/R4)
__device__ __forceinline__ unsigned int pk_trunc(float a, float b) {
  return __builtin_amdgcn_perm(__float_as_uint(b), __float_as_uint(a), 0x07060302u);
}

// ---------------- workspace layout (bytes) ----------------
constexpr size_t O_W1T  = 0;          // 512x1024 bf16
constexpr size_t O_W2TF = 1048576;    // 64x256 bf16
constexpr size_t O_W2TC = 1081344;    // 128x256 bf16
constexpr size_t O_SCLS = 1146880;    // 32x128 f32  [zeroed]
constexpr size_t O_ROWD = 1163264;    // 8192 f32    [zeroed]
constexpr size_t O_ROWN = 1196032;    // 8192 f32    [zeroed]
constexpr size_t O_ROWS = 1228800;    // 8192 f32    [zeroed]
constexpr size_t O_SCAL = 1261568;    // 4 f32       [zeroed]
constexpr size_t O_HIST = 1261584;    // 32 int      [written by meta]
constexpr size_t O_NFG  = 1261712;    // 1 int       [written by meta]
constexpr size_t O_H    = 1261824;    // 8192x512 bf16
constexpr size_t O_ZF   = 9650432;    // 8192x64 bf16 (normalized*scaled)
constexpr size_t O_ZC   = 10699008;   // 8192x128 bf16
constexpr size_t O_XB   = 12796160;   // 8192x1024 bf16 (optional)
constexpr size_t WS_NEED_XB = O_XB + 16777216;   // ~29.6 MB
constexpr int ZERO_WORDS = (int)((O_SCAL + 16 - O_SCLS) / 4);  // 28676

// ---------------- prep: zero | meta | transpose | xconv ----------------
// blocks: [0,113) zero, 113 meta, [114,254) transp, [254,4350) xconv (opt)
__global__ void __launch_bounds__(256) prep_kernel(
    const float* __restrict__ X, const int* __restrict__ labels,
    const float* __restrict__ fgw1, const float* __restrict__ clsw1,
    const float* __restrict__ fgw2, const float* __restrict__ clsw2,
    unsigned short* __restrict__ W1T, unsigned short* __restrict__ W2Tf,
    unsigned short* __restrict__ W2Tc, float* __restrict__ zerop,
    int* __restrict__ hist, int* __restrict__ nfg,
    unsigned short* __restrict__ Xb) {
  const int bx = blockIdx.x, t = threadIdx.x;
  if (bx < 113) {
    int i = bx * 256 + t;
    if (i < ZERO_WORDS) zerop[i] = 0.f;
    return;
  }
  if (bx == 113) {  // meta: single block, direct write
    __shared__ int sh[33];
    if (t < 33) sh[t] = 0;
    __syncthreads();
    for (int it = 0; it < 32; it++) {
      int lab = labels[it * 256 + t];
      if (lab >= 0 && lab < 32) atomicAdd(&sh[lab], 1);
      if (lab > 0) atomicAdd(&sh[32], 1);
    }
    __syncthreads();
    if (t < 32) hist[t] = sh[t];
    if (t == 32) *nfg = sh[32];
    return;
  }
  if (bx < 254) {  // transpose+convert weights (verified R2-R4)
    __shared__ float tile[64][65];
    int lb = bx - 114;
    const float* src; unsigned short* dst; int R, C, lt;
    if (lb < 64)       { src = fgw1;  dst = W1T;              R = 1024; C = 256; lt = lb; }
    else if (lb < 128) { src = clsw1; dst = W1T + 256 * 1024; R = 1024; C = 256; lt = lb - 64; }
    else if (lb < 132) { src = fgw2;  dst = W2Tf;             R = 256;  C = 64;  lt = lb - 128; }
    else               { src = clsw2; dst = W2Tc;             R = 256;  C = 128; lt = lb - 132; }
    const int cT = C >> 6;
    const int r0 = (lt / cT) << 6, c0 = (lt % cT) << 6;
    {
      const int rr = t >> 4, cc = (t & 15) << 2;
#pragma unroll
      for (int i = 0; i < 4; i++) {
        float4 v = *(const float4*)(src + (size_t)(r0 + rr + i * 16) * C + c0 + cc);
        tile[rr + i * 16][cc] = v.x; tile[rr + i * 16][cc + 1] = v.y;
        tile[rr + i * 16][cc + 2] = v.z; tile[rr + i * 16][cc + 3] = v.w;
      }
    }
    __syncthreads();
    {
      const int dr = t >> 2, dc = (t & 3) << 4;
      bs8 o0, o1;
#pragma unroll
      for (int j = 0; j < 8; j++) o0[j] = (short)f2bf(tile[dc + j][dr]);
#pragma unroll
      for (int j = 0; j < 8; j++) o1[j] = (short)f2bf(tile[dc + 8 + j][dr]);
      unsigned short* dp = dst + (size_t)(c0 + dr) * R + r0 + dc;
      *(bs8*)dp = o0;
      *(bs8*)(dp + 8) = o1;
    }
    return;
  }
  {  // xconv: X f32 -> Xb bf16, 8 elems/thread
    int i = (bx - 254) * 2048 + t * 8;
    float4 x0 = *(const float4*)(X + i);
    float4 x1 = *(const float4*)(X + i + 4);
    uint4 pk;
    pk.x = pk_trunc(x0.x, x0.y);
    pk.y = pk_trunc(x0.z, x0.w);
    pk.z = pk_trunc(x1.x, x1.y);
    pk.w = pk_trunc(x1.z, x1.w);
    *(uint4*)(Xb + i) = pk;
  }
}

// ---------------- GEMM1 (bf16 Xb path): H = relu(Xb @ W1 + b1) -------------
__global__ void __launch_bounds__(256) gemm1x_kernel(
    const unsigned short* __restrict__ Xb, const unsigned short* __restrict__ W1T,
    const float* __restrict__ b1f, const float* __restrict__ b1c,
    unsigned short* __restrict__ H) {
  __shared__ __align__(16) unsigned short lA[128 * 72];
  __shared__ __align__(16) unsigned short lB[64 * 72];
  const int t = threadIdx.x;
  const int w = t >> 6, lane = t & 63, ln = lane & 15, quad = lane >> 4;
  const int m0 = blockIdx.x * 128, n0 = blockIdx.y * 64;

  f4 acc[2][4];
#pragma unroll
  for (int rs = 0; rs < 2; rs++)
#pragma unroll
    for (int s = 0; s < 4; s++) acc[rs][s] = (f4){0.f, 0.f, 0.f, 0.f};

  for (int k0 = 0; k0 < 1024; k0 += 64) {
    __syncthreads();
#pragma unroll
    for (int i = 0; i < 4; i++) {
      int c = i * 256 + t, r = c >> 3, ke = (c & 7) * 8;
      *(bs8*)&lA[r * 72 + ke] = *(const bs8*)(Xb + (size_t)(m0 + r) * 1024 + k0 + ke);
    }
#pragma unroll
    for (int i = 0; i < 2; i++) {
      int c = i * 256 + t, r = c >> 3, ke = (c & 7) * 8;
      *(bs8*)&lB[r * 72 + ke] = *(const bs8*)(W1T + (size_t)(n0 + r) * 1024 + k0 + ke);
    }
    __syncthreads();
#pragma unroll
    for (int kk = 0; kk < 2; kk++) {
      bs8 a0 = *(const bs8*)&lA[(w * 32 + ln) * 72 + kk * 32 + quad * 8];
      bs8 a1 = *(const bs8*)&lA[(w * 32 + 16 + ln) * 72 + kk * 32 + quad * 8];
#pragma unroll
      for (int s = 0; s < 4; s++) {
        bs8 bf = *(const bs8*)&lB[(s * 16 + ln) * 72 + kk * 32 + quad * 8];
        acc[0][s] = MFMA_BF16(a0, bf, acc[0][s]);
        acc[1][s] = MFMA_BF16(a1, bf, acc[1][s]);
      }
    }
  }
#pragma unroll
  for (int s = 0; s < 4; s++) {
    int n = n0 + s * 16 + ln;
    float b = (n < 256) ? b1f[n] : b1c[n - 256];
#pragma unroll
    for (int rs = 0; rs < 2; rs++)
#pragma unroll
      for (int r = 0; r < 4; r++) {
        float v = fmaxf(acc[rs][s][r] + b, 0.f);
        H[(size_t)(m0 + w * 32 + rs * 16 + quad * 4 + r) * 512 + n] = f2bf(v);
      }
  }
}

// ---------------- GEMM1 fallback (f32 X, verified R3/R4) ----------------
__global__ void __launch_bounds__(256) gemm1f_kernel(
    const float* __restrict__ X, const unsigned short* __restrict__ W1T,
    const float* __restrict__ b1f, const float* __restrict__ b1c,
    unsigned short* __restrict__ H) {
  __shared__ __align__(16) unsigned short lA[128 * 40];
  __shared__ __align__(16) unsigned short lB[64 * 40];
  const int t = threadIdx.x;
  const int w = t >> 6, lane = t & 63, ln = lane & 15, quad = lane >> 4;
  const int m0 = blockIdx.x * 128, n0 = blockIdx.y * 64;
  f4 acc[2][4];
#pragma unroll
  for (int rs = 0; rs < 2; rs++)
#pragma unroll
    for (int s = 0; s < 4; s++) acc[rs][s] = (f4){0.f, 0.f, 0.f, 0.f};
  for (int k0 = 0; k0 < 1024; k0 += 32) {
    __syncthreads();
#pragma unroll
    for (int i = 0; i < 2; i++) {
      int ch = t + i * 256;
      int r = ch >> 2, c = (ch & 3) * 8;
      const float* xp = X + (size_t)(m0 + r) * 1024 + k0 + c;
      float4 x0 = *(const float4*)xp;
      float4 x1 = *(const float4*)(xp + 4);
      uint4 pk;
      pk.x = pk_trunc(x0.x, x0.y); pk.y = pk_trunc(x0.z, x0.w);
      pk.z = pk_trunc(x1.x, x1.y); pk.w = pk_trunc(x1.z, x1.w);
      *(uint4*)&lA[r * 40 + c] = pk;
    }
    {
      int r = t >> 2, c = (t & 3) * 8;
      *(bs8*)&lB[r * 40 + c] = *(const bs8*)(W1T + (size_t)(n0 + r) * 1024 + k0 + c);
    }
    __syncthreads();
    bs8 af0 = *(const bs8*)&lA[(w * 32 + ln) * 40 + quad * 8];
    bs8 af1 = *(const bs8*)&lA[(w * 32 + 16 + ln) * 40 + quad * 8];
#pragma unroll
    for (int s = 0; s < 4; s++) {
      bs8 bf = *(const bs8*)&lB[(s * 16 + ln) * 40 + quad * 8];
      acc[0][s] = MFMA_BF16(af0, bf, acc[0][s]);
      acc[1][s] = MFMA_BF16(af1, bf, acc[1][s]);
    }
  }
#pragma unroll
  for (int s = 0; s < 4; s++) {
    int n = n0 + s * 16 + ln;
    float b = (n < 256) ? b1f[n] : b1c[n - 256];
#pragma unroll
    for (int rs = 0; rs < 2; rs++)
#pragma unroll
      for (int r = 0; r < 4; r++) {
        float v = fmaxf(acc[rs][s][r] + b, 0.f);
        H[(size_t)(m0 + w * 32 + rs * 16 + quad * 4 + r) * 512 + n] = f2bf(v);
      }
  }
}

// ---------------- GEMM2: Z = SQRT_KL2E * normalize(H @ W2 + b2) ------------
// grid (512): 16 rows/block. w0/w1 = fg K-halves; w2/w3 = cls K-halves.
__global__ void __launch_bounds__(256) gemm2_kernel(
    const unsigned short* __restrict__ H,
    const unsigned short* __restrict__ W2Tf, const unsigned short* __restrict__ W2Tc,
    const float* __restrict__ b2f, const float* __restrict__ b2c,
    unsigned short* __restrict__ Zf, unsigned short* __restrict__ Zc) {
  __shared__ float lredf[64][17];
  __shared__ float lredc[64][33];
  const int t = threadIdx.x;
  const int w = t >> 6, lane = t & 63, ln = lane & 15, quad = lane >> 4;
  const int rw = blockIdx.x * 16;
  const int kh = w & 1;

  if (w < 2) {  // fg head, K-half kh
    const unsigned short* hrow = H + (size_t)(rw + ln) * 512 + kh * 128;
    f4 acc[4];
#pragma unroll
    for (int s = 0; s < 4; s++) acc[s] = (f4){0.f, 0.f, 0.f, 0.f};
#pragma unroll
    for (int ks = 0; ks < 4; ks++) {
      bs8 af = *(const bs8*)(hrow + ks * 32 + quad * 8);
#pragma unroll
      for (int s = 0; s < 4; s++) {
        bs8 bf = *(const bs8*)(W2Tf + (size_t)(s * 16 + ln) * 256 + kh * 128 + ks * 32 + quad * 8);
        acc[s] = MFMA_BF16(af, bf, acc[s]);
      }
    }
    if (kh) {
#pragma unroll
      for (int s = 0; s < 4; s++)
#pragma unroll
        for (int r = 0; r < 4; r++) lredf[lane][s * 4 + r] = acc[s][r];
    }
    __syncthreads();
    if (w == 0) {
      float ss[4] = {0.f, 0.f, 0.f, 0.f};
#pragma unroll
      for (int s = 0; s < 4; s++) {
        float b = b2f[s * 16 + ln];
#pragma unroll
        for (int r = 0; r < 4; r++) {
          acc[s][r] += lredf[lane][s * 4 + r] + b;
          ss[r] = fmaf(acc[s][r], acc[s][r], ss[r]);
        }
      }
#pragma unroll
      for (int r = 0; r < 4; r++) {
#pragma unroll
        for (int off = 1; off < 16; off <<= 1) ss[r] += __shfl_xor(ss[r], off, 64);
        float sc = SQRT_KL2E / fmaxf(sqrtf(ss[r]), 1e-8f);
#pragma unroll
        for (int s = 0; s < 4; s++)
          Zf[(size_t)(rw + quad * 4 + r) * 64 + s * 16 + ln] = f2bf(acc[s][r] * sc);
      }
    }
  } else {  // cls head, K-half kh
    const unsigned short* hrow = H + (size_t)(rw + ln) * 512 + 256 + kh * 128;
    f4 acc[8];
#pragma unroll
    for (int s = 0; s < 8; s++) acc[s] = (f4){0.f, 0.f, 0.f, 0.f};
#pragma unroll
    for (int ks = 0; ks < 4; ks++) {
      bs8 af = *(const bs8*)(hrow + ks * 32 + quad * 8);
#pragma unroll
      for (int s = 0; s < 8; s++) {
        bs8 bf = *(const bs8*)(W2Tc + (size_t)(s * 16 + ln) * 256 + kh * 128 + ks * 32 + quad * 8);
        acc[s] = MFMA_BF16(af, bf, acc[s]);
      }
    }
    if (kh) {
#pragma unroll
      for (int s = 0; s < 8; s++)
#pragma unroll
        for (int r = 0; r < 4; r++) lredc[lane][s * 4 + r] = acc[s][r];
    }
    __syncthreads();
    if (w == 2) {
      float ss[4] = {0.f, 0.f, 0.f, 0.f};
#pragma unroll
      for (int s = 0; s < 8; s++) {
        float b = b2c[s * 16 + ln];
#pragma unroll
        for (int r = 0; r < 4; r++) {
          acc[s][r] += lredc[lane][s * 4 + r] + b;
          ss[r] = fmaf(acc[s][r], acc[s][r], ss[r]);
        }
      }
#pragma unroll
      for (int r = 0; r < 4; r++) {
#pragma unroll
        for (int off = 1; off < 16; off <<= 1) ss[r] += __shfl_xor(ss[r], off, 64);
        float sc = SQRT_KL2E / fmaxf(sqrtf(ss[r]), 1e-8f);
#pragma unroll
        for (int s = 0; s < 8; s++)
          Zc[(size_t)(rw + quad * 4 + r) * 128 + s * 16 + ln] = f2bf(acc[s][r] * sc);
      }
    }
  }
}

// ---------------- class sums: one pass, LDS accumulator ----------------
// grid (32), 128 threads; block handles 256 rows; lacc[class][col] in LDS.
__global__ void __launch_bounds__(128) scls_kernel(const unsigned short* __restrict__ Zc,
                                                   const int* __restrict__ labels,
                                                   float* __restrict__ Scls) {
  __shared__ float lacc[21][128];
  const int t = threadIdx.x;
#pragma unroll
  for (int c = 0; c < 21; c++) lacc[c][t] = 0.f;
  const int r0 = blockIdx.x * 256;
#pragma unroll 4
  for (int r = r0; r < r0 + 256; r++) {
    const int lab = labels[r];
    if (lab > 0) lacc[lab][t] += bf2f(Zc[(size_t)r * 128 + t]);
  }
#pragma unroll
  for (int c = 1; c < 21; c++) atomicAdd(&Scls[c * 128 + t], lacc[c][t]);
}

// ---------------- fused NxN sim reductions ----------------
// grid (64, 16): 128 rows x 512 cols per block; 4 col-tiles of 128 staged in
// LDS. Raw v_exp_f32. Diagonal included; corrected in finalize.
__global__ void __launch_bounds__(256, 3) sim_kernel(
    const unsigned short* __restrict__ Zf, const unsigned short* __restrict__ Zc,
    const int* __restrict__ labels,
    float* __restrict__ rowD, float* __restrict__ rowN, float* __restrict__ rowS) {
  __shared__ __align__(16) unsigned short sZf[128 * 68];
  __shared__ __align__(16) unsigned short sZc[128 * 132];
  __shared__ float sFg[128];
  const int t = threadIdx.x;
  const int w = t >> 6, lane = t & 63, ln = lane & 15, quad = lane >> 4;
  const int rbase = blockIdx.x * 128 + w * 32;

  // row fragments (registers, loop-invariant)
  bs8 afg[2][2], acl[2][4];
#pragma unroll
  for (int rs = 0; rs < 2; rs++) {
    const unsigned short* zf = Zf + (size_t)(rbase + rs * 16 + ln) * 64;
    const unsigned short* zc = Zc + (size_t)(rbase + rs * 16 + ln) * 128;
#pragma unroll
    for (int s = 0; s < 2; s++) afg[rs][s] = *(const bs8*)(zf + s * 32 + quad * 8);
#pragma unroll
    for (int s = 0; s < 4; s++) acl[rs][s] = *(const bs8*)(zc + s * 32 + quad * 8);
  }

  float dacc[2][4] = {}, nacc[2][4] = {}, sacc[2][4] = {};

  for (int ct = 0; ct < 4; ct++) {
    const int c0 = blockIdx.y * 512 + ct * 128;
    if (ct) __syncthreads();
    // stage 128-col tile (fg64 + cls128)
#pragma unroll
    for (int i = 0; i < 4; i++) {
      int c = i * 256 + t, j = c >> 3, k8 = (c & 7) * 8;
      *(bs8*)&sZf[j * 68 + k8] = *(const bs8*)(Zf + (size_t)(c0 + j) * 64 + k8);
    }
#pragma unroll
    for (int i = 0; i < 8; i++) {
      int c = i * 256 + t, j = c >> 4, k8 = (c & 15) * 8;
      *(bs8*)&sZc[j * 132 + k8] = *(const bs8*)(Zc + (size_t)(c0 + j) * 128 + k8);
    }
    if (t < 128) sFg[t] = (labels[c0 + t] > 0) ? 1.f : 0.f;
    __syncthreads();

#pragma unroll 2
    for (int cg = 0; cg < 8; cg++) {
      const int lcol = cg * 16 + ln;
      const float fgc = sFg[lcol];
      bs8 b0 = *(const bs8*)&sZf[lcol * 68 + quad * 8];
      bs8 b1 = *(const bs8*)&sZf[lcol * 68 + 32 + quad * 8];
      bs8 bc0 = *(const bs8*)&sZc[lcol * 132 + quad * 8];
      bs8 bc1 = *(const bs8*)&sZc[lcol * 132 + 32 + quad * 8];
      bs8 bc2 = *(const bs8*)&sZc[lcol * 132 + 64 + quad * 8];
      bs8 bc3 = *(const bs8*)&sZc[lcol * 132 + 96 + quad * 8];
#pragma unroll
      for (int rs = 0; rs < 2; rs++) {
        f4 cf = {0.f, 0.f, 0.f, 0.f};
        cf = MFMA_BF16(afg[rs][0], b0, cf);
        cf = MFMA_BF16(afg[rs][1], b1, cf);
#pragma unroll
        for (int r = 0; r < 4; r++) {
          float e = EXP2F(cf[r]);
          dacc[rs][r] += e;
          nacc[rs][r] = fmaf(fgc, e, nacc[rs][r]);
        }
        f4 cs = {0.f, 0.f, 0.f, 0.f};
        cs = MFMA_BF16(acl[rs][0], bc0, cs);
        cs = MFMA_BF16(acl[rs][1], bc1, cs);
        cs = MFMA_BF16(acl[rs][2], bc2, cs);
        cs = MFMA_BF16(acl[rs][3], bc3, cs);
#pragma unroll
        for (int r = 0; r < 4; r++) sacc[rs][r] += EXP2F(cs[r]);
      }
    }
  }

#pragma unroll
  for (int rs = 0; rs < 2; rs++)
#pragma unroll
    for (int r = 0; r < 4; r++) {
      float d = dacc[rs][r], n = nacc[rs][r], s = sacc[rs][r];
#pragma unroll
      for (int off = 1; off < 16; off <<= 1) {
        d += __shfl_xor(d, off, 64);
        n += __shfl_xor(n, off, 64);
        s += __shfl_xor(s, off, 64);
      }
      if (ln == 0) {
        int row = rbase + rs * 16 + quad * 4 + r;
        atomicAdd(&rowD[row], d);
        atomicAdd(&rowN[row], n);
        atomicAdd(&rowS[row], s);
      }
    }
}

// ---------------- per-row losses (scaled-space corrections, verified) -------
__global__ void __launch_bounds__(256) finalize_kernel(
    const unsigned short* __restrict__ Zf, const unsigned short* __restrict__ Zc,
    const int* __restrict__ labels, const float* __restrict__ ious,
    const float* __restrict__ rowD, const float* __restrict__ rowN,
    const float* __restrict__ rowS, const float* __restrict__ Scls,
    const int* __restrict__ hist, const int* __restrict__ nfg,
    float* __restrict__ scal) {
  __shared__ float red[4][4];
  const int t = threadIdx.x, w = t >> 6, lane = t & 63;
  float aw0 = 0.f, al0 = 0.f, aw1 = 0.f, al1 = 0.f;
  const int NFG = *nfg;
  for (int it = 0; it < 16; it++) {
    const int i = it * 512 + blockIdx.x * 4 + w;
    const int lab = labels[i];
    if (lab > 0 && lab < 32) {
      const float iou = ious[i];
      const float iw = (iou > 0.5f) ? iou : 0.f;
      float dot = 0.f, ssq = 0.f;
#pragma unroll
      for (int p = 0; p < 2; p++) {
        const int k = lane + p * 64;
        const float z = bf2f(Zc[(size_t)i * 128 + k]);
        dot = fmaf(z, Scls[lab * 128 + k], dot);
        ssq = fmaf(z, z, ssq);
      }
      float zf = bf2f(Zf[(size_t)i * 64 + lane]);
      float ssqf = zf * zf;
#pragma unroll
      for (int off = 1; off < 64; off <<= 1) {
        dot += __shfl_xor(dot, off, 64);
        ssq += __shfl_xor(ssq, off, 64);
        ssqf += __shfl_xor(ssqf, off, 64);
      }
      if (lane == 0) {
        const float ef = EXP2F(ssqf);
        if (NFG - 1 > 0) {
          const float D = rowD[i] - ef;
          const float Nn = rowN[i] - ef;
          const float loss = logf(D + 2e-8f) - logf(Nn + 1e-8f);
          aw0 += iw;
          al0 += iw * loss;
        }
        const int npc = hist[lab];
        if (npc > 0) {
          const float S = rowS[i] - EXP2F(ssq);
          const float logden = logf(S);
          const float slp = (dot - ssq) * LN2F - (float)(npc - 1) * logden - 1e9f;
          aw1 += iw;
          al1 += iw * (-slp / ((float)npc + 1e-8f));
        }
      }
    }
  }
  if (lane == 0) { red[w][0] = aw0; red[w][1] = al0; red[w][2] = aw1; red[w][3] = al1; }
  __syncthreads();
  if (t < 4) atomicAdd(&scal[t], red[0][t] + red[1][t] + red[2][t] + red[3][t]);
}

__global__ void writeout_kernel(const float* __restrict__ scal, float* __restrict__ out) {
  if (threadIdx.x == 0) {
    out[0] = scal[1] / (scal[0] + 1e-8f);
    out[1] = scal[3] / (scal[2] + 1e-8f);
  }
}

// ---------------- launch ----------------
extern "C" void kernel_launch(void* const* d_in, const int* in_sizes, int n_in,
                              void* d_out, int out_size, void* d_ws, size_t ws_size,
                              hipStream_t stream) {
  (void)in_sizes; (void)n_in; (void)out_size;
  const float* roi    = (const float*)d_in[0];
  const int*   labels = (const int*)d_in[1];
  const float* ious   = (const float*)d_in[2];
  const float* fgw1   = (const float*)d_in[3];
  const float* fgb1   = (const float*)d_in[4];
  const float* fgw2   = (const float*)d_in[5];
  const float* fgb2   = (const float*)d_in[6];
  const float* clsw1  = (const float*)d_in[7];
  const float* clsb1  = (const float*)d_in[8];
  const float* clsw2  = (const float*)d_in[9];
  const float* clsb2  = (const float*)d_in[10];

  char* ws = (char*)d_ws;
  unsigned short* W1T  = (unsigned short*)(ws + O_W1T);
  unsigned short* W2Tf = (unsigned short*)(ws + O_W2TF);
  unsigned short* W2Tc = (unsigned short*)(ws + O_W2TC);
  unsigned short* Hb   = (unsigned short*)(ws + O_H);
  unsigned short* Zf   = (unsigned short*)(ws + O_ZF);
  unsigned short* Zc   = (unsigned short*)(ws + O_ZC);
  unsigned short* Xb   = (unsigned short*)(ws + O_XB);
  float* Scls = (float*)(ws + O_SCLS);
  float* rowD = (float*)(ws + O_ROWD);
  float* rowN = (float*)(ws + O_ROWN);
  float* rowS = (float*)(ws + O_ROWS);
  float* scal = (float*)(ws + O_SCAL);
  int* hist = (int*)(ws + O_HIST);
  int* nfg  = (int*)(ws + O_NFG);
  float* out = (float*)d_out;

  const bool useXb = ws_size >= WS_NEED_XB;
  const int prepBlocks = useXb ? 4350 : 254;

  hipLaunchKernelGGL(prep_kernel, dim3(prepBlocks), dim3(256), 0, stream,
                     roi, labels, fgw1, clsw1, fgw2, clsw2,
                     W1T, W2Tf, W2Tc, (float*)(ws + O_SCLS), hist, nfg, Xb);
  if (useXb) {
    hipLaunchKernelGGL(gemm1x_kernel, dim3(64, 8), dim3(256), 0, stream,
                       Xb, W1T, fgb1, clsb1, Hb);
  } else {
    hipLaunchKernelGGL(gemm1f_kernel, dim3(64, 8), dim3(256), 0, stream,
                       roi, W1T, fgb1, clsb1, Hb);
  }
  hipLaunchKernelGGL(gemm2_kernel, dim3(512), dim3(256), 0, stream,
                     Hb, W2Tf, W2Tc, fgb2, clsb2, Zf, Zc);
  hipLaunchKernelGGL(scls_kernel, dim3(32), dim3(128), 0, stream, Zc, labels, Scls);
  hipLaunchKernelGGL(sim_kernel, dim3(64, 16), dim3(256), 0, stream,
                     Zf, Zc, labels, rowD, rowN, rowS);
  hipLaunchKernelGGL(finalize_kernel, dim3(128), dim3(256), 0, stream,
                     Zf, Zc, labels, ious, rowD, rowN, rowS, Scls, hist, nfg, scal);
  hipLaunchKernelGGL(writeout_kernel, dim3(1), dim3(64), 0, stream, scal, out);
}

// Round 6
// 222.386 us; speedup vs baseline: 1.2880x; 1.2880x over previous
//
#include <hip/hip_runtime.h>

// MultiHeadContrastive on MI355X (gfx950).
// prep (fused: zero + meta + weight-transpose + X->bf16) -> GEMM1 -> GEMM2
//   (normalize, scale by sqrt(5*log2e)) -> class sums -> fused NxN sim
//   (col tiles staged in LDS, raw v_exp_f32) -> finalize -> out.
// Z stored PRE-SCALED: zs = sqrt(5*log2e)*z so 2^(zs_i.zs_j) = exp(sim/tau).

typedef __attribute__((ext_vector_type(8))) short bs8;   // 8 x bf16
typedef __attribute__((ext_vector_type(4))) float f4;    // MFMA accumulator

#define MFMA_BF16(a, b, c) __builtin_amdgcn_mfma_f32_16x16x32_bf16((a), (b), (c), 0, 0, 0)

// raw v_exp_f32 — NEVER ocml exp2f (R4 post-mortem: +17us of VALU fixup code)
#if defined(__has_builtin)
#if __has_builtin(__builtin_amdgcn_exp2f)
#define EXP2F(x) __builtin_amdgcn_exp2f(x)
#endif
#endif
#ifndef EXP2F
__device__ __forceinline__ float __exp2_raw(float x) {
  float r;
  asm volatile("v_exp_f32 %0, %1" : "=v"(r) : "v"(x));
  return r;
}
#define EXP2F(x) __exp2_raw(x)
#endif

#define SQRT_KL2E 2.6857914f    // sqrt(5 * log2(e))
#define LN2F      0.6931471805599453f

__device__ __forceinline__ unsigned short f2bf(float f) {
  unsigned int u = __float_as_uint(f);
  u = (u + 0x7fffu + ((u >> 16) & 1u)) >> 16;   // RNE
  return (unsigned short)u;
}
__device__ __forceinline__ float bf2f(unsigned short s) {
  return __uint_as_float(((unsigned int)s) << 16);
}
// pack two f32 -> two bf16 (truncation) in ONE v_perm_b32 (verified R3-R5)
__device__ __forceinline__ unsigned int pk_trunc(float a, float b) {
  return __builtin_amdgcn_perm(__float_as_uint(b), __float_as_uint(a), 0x07060302u);
}

// ---------------- workspace layout (bytes) ----------------
constexpr size_t O_W1T  = 0;          // 512x1024 bf16
constexpr size_t O_W2TF = 1048576;    // 64x256 bf16
constexpr size_t O_W2TC = 1081344;    // 128x256 bf16
constexpr size_t O_SCLS = 1146880;    // 32x128 f32  [zeroed]
constexpr size_t O_ROWD = 1163264;    // 8192 f32    [zeroed]
constexpr size_t O_ROWN = 1196032;    // 8192 f32    [zeroed]
constexpr size_t O_ROWS = 1228800;    // 8192 f32    [zeroed]
constexpr size_t O_SCAL = 1261568;    // 4 f32       [zeroed]
constexpr size_t O_HIST = 1261584;    // 32 int      [written by meta]
constexpr size_t O_NFG  = 1261712;    // 1 int       [written by meta]
constexpr size_t O_H    = 1261824;    // 8192x512 bf16
constexpr size_t O_ZF   = 9650432;    // 8192x64 bf16 (normalized*scaled)
constexpr size_t O_ZC   = 10699008;   // 8192x128 bf16
constexpr size_t O_XB   = 12796160;   // 8192x1024 bf16 (optional)
constexpr size_t WS_NEED_XB = O_XB + 16777216;   // ~29.6 MB
constexpr int ZERO_WORDS = (int)((O_SCAL + 16 - O_SCLS) / 4);  // 28676

// ---------------- prep: zero | meta | transpose | xconv ----------------
// blocks: [0,113) zero, 113 meta, [114,254) transp, [254,4350) xconv (opt)
__global__ void __launch_bounds__(256) prep_kernel(
    const float* __restrict__ X, const int* __restrict__ labels,
    const float* __restrict__ fgw1, const float* __restrict__ clsw1,
    const float* __restrict__ fgw2, const float* __restrict__ clsw2,
    unsigned short* __restrict__ W1T, unsigned short* __restrict__ W2Tf,
    unsigned short* __restrict__ W2Tc, float* __restrict__ zerop,
    int* __restrict__ hist, int* __restrict__ nfg,
    unsigned short* __restrict__ Xb) {
  const int bx = blockIdx.x, t = threadIdx.x;
  if (bx < 113) {
    int i = bx * 256 + t;
    if (i < ZERO_WORDS) zerop[i] = 0.f;
    return;
  }
  if (bx == 113) {  // meta: single block, direct write
    __shared__ int sh[33];
    if (t < 33) sh[t] = 0;
    __syncthreads();
    for (int it = 0; it < 32; it++) {
      int lab = labels[it * 256 + t];
      if (lab >= 0 && lab < 32) atomicAdd(&sh[lab], 1);
      if (lab > 0) atomicAdd(&sh[32], 1);
    }
    __syncthreads();
    if (t < 32) hist[t] = sh[t];
    if (t == 32) *nfg = sh[32];
    return;
  }
  if (bx < 254) {  // transpose+convert weights (verified R2-R5)
    __shared__ float tile[64][65];
    int lb = bx - 114;
    const float* src; unsigned short* dst; int R, C, lt;
    if (lb < 64)       { src = fgw1;  dst = W1T;              R = 1024; C = 256; lt = lb; }
    else if (lb < 128) { src = clsw1; dst = W1T + 256 * 1024; R = 1024; C = 256; lt = lb - 64; }
    else if (lb < 132) { src = fgw2;  dst = W2Tf;             R = 256;  C = 64;  lt = lb - 128; }
    else               { src = clsw2; dst = W2Tc;             R = 256;  C = 128; lt = lb - 132; }
    const int cT = C >> 6;
    const int r0 = (lt / cT) << 6, c0 = (lt % cT) << 6;
    {
      const int rr = t >> 4, cc = (t & 15) << 2;
#pragma unroll
      for (int i = 0; i < 4; i++) {
        float4 v = *(const float4*)(src + (size_t)(r0 + rr + i * 16) * C + c0 + cc);
        tile[rr + i * 16][cc] = v.x; tile[rr + i * 16][cc + 1] = v.y;
        tile[rr + i * 16][cc + 2] = v.z; tile[rr + i * 16][cc + 3] = v.w;
      }
    }
    __syncthreads();
    {
      const int dr = t >> 2, dc = (t & 3) << 4;
      bs8 o0, o1;
#pragma unroll
      for (int j = 0; j < 8; j++) o0[j] = (short)f2bf(tile[dc + j][dr]);
#pragma unroll
      for (int j = 0; j < 8; j++) o1[j] = (short)f2bf(tile[dc + 8 + j][dr]);
      unsigned short* dp = dst + (size_t)(c0 + dr) * R + r0 + dc;
      *(bs8*)dp = o0;
      *(bs8*)(dp + 8) = o1;
    }
    return;
  }
  {  // xconv: X f32 -> Xb bf16, 8 elems/thread
    int i = (bx - 254) * 2048 + t * 8;
    float4 x0 = *(const float4*)(X + i);
    float4 x1 = *(const float4*)(X + i + 4);
    uint4 pk;
    pk.x = pk_trunc(x0.x, x0.y);
    pk.y = pk_trunc(x0.z, x0.w);
    pk.z = pk_trunc(x1.x, x1.y);
    pk.w = pk_trunc(x1.z, x1.w);
    *(uint4*)(Xb + i) = pk;
  }
}

// ---------------- GEMM1 (bf16 Xb path): H = relu(Xb @ W1 + b1) -------------
__global__ void __launch_bounds__(256) gemm1x_kernel(
    const unsigned short* __restrict__ Xb, const unsigned short* __restrict__ W1T,
    const float* __restrict__ b1f, const float* __restrict__ b1c,
    unsigned short* __restrict__ H) {
  __shared__ __align__(16) unsigned short lA[128 * 72];
  __shared__ __align__(16) unsigned short lB[64 * 72];
  const int t = threadIdx.x;
  const int w = t >> 6, lane = t & 63, ln = lane & 15, quad = lane >> 4;
  const int m0 = blockIdx.x * 128, n0 = blockIdx.y * 64;

  f4 acc[2][4];
#pragma unroll
  for (int rs = 0; rs < 2; rs++)
#pragma unroll
    for (int s = 0; s < 4; s++) acc[rs][s] = (f4){0.f, 0.f, 0.f, 0.f};

  for (int k0 = 0; k0 < 1024; k0 += 64) {
    __syncthreads();
#pragma unroll
    for (int i = 0; i < 4; i++) {
      int c = i * 256 + t, r = c >> 3, ke = (c & 7) * 8;
      *(bs8*)&lA[r * 72 + ke] = *(const bs8*)(Xb + (size_t)(m0 + r) * 1024 + k0 + ke);
    }
#pragma unroll
    for (int i = 0; i < 2; i++) {
      int c = i * 256 + t, r = c >> 3, ke = (c & 7) * 8;
      *(bs8*)&lB[r * 72 + ke] = *(const bs8*)(W1T + (size_t)(n0 + r) * 1024 + k0 + ke);
    }
    __syncthreads();
#pragma unroll
    for (int kk = 0; kk < 2; kk++) {
      bs8 a0 = *(const bs8*)&lA[(w * 32 + ln) * 72 + kk * 32 + quad * 8];
      bs8 a1 = *(const bs8*)&lA[(w * 32 + 16 + ln) * 72 + kk * 32 + quad * 8];
#pragma unroll
      for (int s = 0; s < 4; s++) {
        bs8 bf = *(const bs8*)&lB[(s * 16 + ln) * 72 + kk * 32 + quad * 8];
        acc[0][s] = MFMA_BF16(a0, bf, acc[0][s]);
        acc[1][s] = MFMA_BF16(a1, bf, acc[1][s]);
      }
    }
  }
#pragma unroll
  for (int s = 0; s < 4; s++) {
    int n = n0 + s * 16 + ln;
    float b = (n < 256) ? b1f[n] : b1c[n - 256];
#pragma unroll
    for (int rs = 0; rs < 2; rs++)
#pragma unroll
      for (int r = 0; r < 4; r++) {
        float v = fmaxf(acc[rs][s][r] + b, 0.f);
        H[(size_t)(m0 + w * 32 + rs * 16 + quad * 4 + r) * 512 + n] = f2bf(v);
      }
  }
}

// ---------------- GEMM1 fallback (f32 X, verified R3-R5) ----------------
__global__ void __launch_bounds__(256) gemm1f_kernel(
    const float* __restrict__ X, const unsigned short* __restrict__ W1T,
    const float* __restrict__ b1f, const float* __restrict__ b1c,
    unsigned short* __restrict__ H) {
  __shared__ __align__(16) unsigned short lA[128 * 40];
  __shared__ __align__(16) unsigned short lB[64 * 40];
  const int t = threadIdx.x;
  const int w = t >> 6, lane = t & 63, ln = lane & 15, quad = lane >> 4;
  const int m0 = blockIdx.x * 128, n0 = blockIdx.y * 64;
  f4 acc[2][4];
#pragma unroll
  for (int rs = 0; rs < 2; rs++)
#pragma unroll
    for (int s = 0; s < 4; s++) acc[rs][s] = (f4){0.f, 0.f, 0.f, 0.f};
  for (int k0 = 0; k0 < 1024; k0 += 32) {
    __syncthreads();
#pragma unroll
    for (int i = 0; i < 2; i++) {
      int ch = t + i * 256;
      int r = ch >> 2, c = (ch & 3) * 8;
      const float* xp = X + (size_t)(m0 + r) * 1024 + k0 + c;
      float4 x0 = *(const float4*)xp;
      float4 x1 = *(const float4*)(xp + 4);
      uint4 pk;
      pk.x = pk_trunc(x0.x, x0.y); pk.y = pk_trunc(x0.z, x0.w);
      pk.z = pk_trunc(x1.x, x1.y); pk.w = pk_trunc(x1.z, x1.w);
      *(uint4*)&lA[r * 40 + c] = pk;
    }
    {
      int r = t >> 2, c = (t & 3) * 8;
      *(bs8*)&lB[r * 40 + c] = *(const bs8*)(W1T + (size_t)(n0 + r) * 1024 + k0 + c);
    }
    __syncthreads();
    bs8 af0 = *(const bs8*)&lA[(w * 32 + ln) * 40 + quad * 8];
    bs8 af1 = *(const bs8*)&lA[(w * 32 + 16 + ln) * 40 + quad * 8];
#pragma unroll
    for (int s = 0; s < 4; s++) {
      bs8 bf = *(const bs8*)&lB[(s * 16 + ln) * 40 + quad * 8];
      acc[0][s] = MFMA_BF16(af0, bf, acc[0][s]);
      acc[1][s] = MFMA_BF16(af1, bf, acc[1][s]);
    }
  }
#pragma unroll
  for (int s = 0; s < 4; s++) {
    int n = n0 + s * 16 + ln;
    float b = (n < 256) ? b1f[n] : b1c[n - 256];
#pragma unroll
    for (int rs = 0; rs < 2; rs++)
#pragma unroll
      for (int r = 0; r < 4; r++) {
        float v = fmaxf(acc[rs][s][r] + b, 0.f);
        H[(size_t)(m0 + w * 32 + rs * 16 + quad * 4 + r) * 512 + n] = f2bf(v);
      }
  }
}

// ---------------- GEMM2: Z = SQRT_KL2E * normalize(H @ W2 + b2) ------------
// grid (512): 16 rows/block. w0/w1 = fg K-halves; w2/w3 = cls K-halves.
__global__ void __launch_bounds__(256) gemm2_kernel(
    const unsigned short* __restrict__ H,
    const unsigned short* __restrict__ W2Tf, const unsigned short* __restrict__ W2Tc,
    const float* __restrict__ b2f, const float* __restrict__ b2c,
    unsigned short* __restrict__ Zf, unsigned short* __restrict__ Zc) {
  __shared__ float lredf[64][17];
  __shared__ float lredc[64][33];
  const int t = threadIdx.x;
  const int w = t >> 6, lane = t & 63, ln = lane & 15, quad = lane >> 4;
  const int rw = blockIdx.x * 16;
  const int kh = w & 1;

  if (w < 2) {  // fg head, K-half kh
    const unsigned short* hrow = H + (size_t)(rw + ln) * 512 + kh * 128;
    f4 acc[4];
#pragma unroll
    for (int s = 0; s < 4; s++) acc[s] = (f4){0.f, 0.f, 0.f, 0.f};
#pragma unroll
    for (int ks = 0; ks < 4; ks++) {
      bs8 af = *(const bs8*)(hrow + ks * 32 + quad * 8);
#pragma unroll
      for (int s = 0; s < 4; s++) {
        bs8 bf = *(const bs8*)(W2Tf + (size_t)(s * 16 + ln) * 256 + kh * 128 + ks * 32 + quad * 8);
        acc[s] = MFMA_BF16(af, bf, acc[s]);
      }
    }
    if (kh) {
#pragma unroll
      for (int s = 0; s < 4; s++)
#pragma unroll
        for (int r = 0; r < 4; r++) lredf[lane][s * 4 + r] = acc[s][r];
    }
    __syncthreads();
    if (w == 0) {
      float ss[4] = {0.f, 0.f, 0.f, 0.f};
#pragma unroll
      for (int s = 0; s < 4; s++) {
        float b = b2f[s * 16 + ln];
#pragma unroll
        for (int r = 0; r < 4; r++) {
          acc[s][r] += lredf[lane][s * 4 + r] + b;
          ss[r] = fmaf(acc[s][r], acc[s][r], ss[r]);
        }
      }
#pragma unroll
      for (int r = 0; r < 4; r++) {
#pragma unroll
        for (int off = 1; off < 16; off <<= 1) ss[r] += __shfl_xor(ss[r], off, 64);
        float sc = SQRT_KL2E / fmaxf(sqrtf(ss[r]), 1e-8f);
#pragma unroll
        for (int s = 0; s < 4; s++)
          Zf[(size_t)(rw + quad * 4 + r) * 64 + s * 16 + ln] = f2bf(acc[s][r] * sc);
      }
    }
  } else {  // cls head, K-half kh
    const unsigned short* hrow = H + (size_t)(rw + ln) * 512 + 256 + kh * 128;
    f4 acc[8];
#pragma unroll
    for (int s = 0; s < 8; s++) acc[s] = (f4){0.f, 0.f, 0.f, 0.f};
#pragma unroll
    for (int ks = 0; ks < 4; ks++) {
      bs8 af = *(const bs8*)(hrow + ks * 32 + quad * 8);
#pragma unroll
      for (int s = 0; s < 8; s++) {
        bs8 bf = *(const bs8*)(W2Tc + (size_t)(s * 16 + ln) * 256 + kh * 128 + ks * 32 + quad * 8);
        acc[s] = MFMA_BF16(af, bf, acc[s]);
      }
    }
    if (kh) {
#pragma unroll
      for (int s = 0; s < 8; s++)
#pragma unroll
        for (int r = 0; r < 4; r++) lredc[lane][s * 4 + r] = acc[s][r];
    }
    __syncthreads();
    if (w == 2) {
      float ss[4] = {0.f, 0.f, 0.f, 0.f};
#pragma unroll
      for (int s = 0; s < 8; s++) {
        float b = b2c[s * 16 + ln];
#pragma unroll
        for (int r = 0; r < 4; r++) {
          acc[s][r] += lredc[lane][s * 4 + r] + b;
          ss[r] = fmaf(acc[s][r], acc[s][r], ss[r]);
        }
      }
#pragma unroll
      for (int r = 0; r < 4; r++) {
#pragma unroll
        for (int off = 1; off < 16; off <<= 1) ss[r] += __shfl_xor(ss[r], off, 64);
        float sc = SQRT_KL2E / fmaxf(sqrtf(ss[r]), 1e-8f);
#pragma unroll
        for (int s = 0; s < 8; s++)
          Zc[(size_t)(rw + quad * 4 + r) * 128 + s * 16 + ln] = f2bf(acc[s][r] * sc);
      }
    }
  }
}

// ---------------- class sums: per-class sweep, register accumulator ---------
// grid (20, 64): class = bx+1, 128 rows/block. R2-proven pattern (R5's LDS
// one-pass collapsed to 0.65% occupancy / 73us — never again).
__global__ void __launch_bounds__(128) scls_kernel(const unsigned short* __restrict__ Zc,
                                                   const int* __restrict__ labels,
                                                   float* __restrict__ Scls) {
  const int c = blockIdx.x + 1;
  const int t = threadIdx.x;
  const int r0 = blockIdx.y * 128;
  float acc = 0.f;
#pragma unroll 4
  for (int r = r0; r < r0 + 128; r++) {
    if (labels[r] == c) acc += bf2f(Zc[(size_t)r * 128 + t]);
  }
  atomicAdd(&Scls[c * 128 + t], acc);
}

// ---------------- fused NxN sim reductions ----------------
// grid (64, 16): 128 rows x 512 cols per block; 4 col-tiles of 128 staged in
// LDS. Raw v_exp_f32. Diagonal included; corrected in finalize.
__global__ void __launch_bounds__(256, 3) sim_kernel(
    const unsigned short* __restrict__ Zf, const unsigned short* __restrict__ Zc,
    const int* __restrict__ labels,
    float* __restrict__ rowD, float* __restrict__ rowN, float* __restrict__ rowS) {
  __shared__ __align__(16) unsigned short sZf[128 * 68];
  __shared__ __align__(16) unsigned short sZc[128 * 132];
  __shared__ float sFg[128];
  const int t = threadIdx.x;
  const int w = t >> 6, lane = t & 63, ln = lane & 15, quad = lane >> 4;
  const int rbase = blockIdx.x * 128 + w * 32;

  // row fragments (registers, loop-invariant)
  bs8 afg[2][2], acl[2][4];
#pragma unroll
  for (int rs = 0; rs < 2; rs++) {
    const unsigned short* zf = Zf + (size_t)(rbase + rs * 16 + ln) * 64;
    const unsigned short* zc = Zc + (size_t)(rbase + rs * 16 + ln) * 128;
#pragma unroll
    for (int s = 0; s < 2; s++) afg[rs][s] = *(const bs8*)(zf + s * 32 + quad * 8);
#pragma unroll
    for (int s = 0; s < 4; s++) acl[rs][s] = *(const bs8*)(zc + s * 32 + quad * 8);
  }

  float dacc[2][4] = {}, nacc[2][4] = {}, sacc[2][4] = {};

  for (int ct = 0; ct < 4; ct++) {
    const int c0 = blockIdx.y * 512 + ct * 128;
    if (ct) __syncthreads();
    // stage 128-col tile (fg64 + cls128)
#pragma unroll
    for (int i = 0; i < 4; i++) {
      int c = i * 256 + t, j = c >> 3, k8 = (c & 7) * 8;
      *(bs8*)&sZf[j * 68 + k8] = *(const bs8*)(Zf + (size_t)(c0 + j) * 64 + k8);
    }
#pragma unroll
    for (int i = 0; i < 8; i++) {
      int c = i * 256 + t, j = c >> 4, k8 = (c & 15) * 8;
      *(bs8*)&sZc[j * 132 + k8] = *(const bs8*)(Zc + (size_t)(c0 + j) * 128 + k8);
    }
    if (t < 128) sFg[t] = (labels[c0 + t] > 0) ? 1.f : 0.f;
    __syncthreads();

#pragma unroll 2
    for (int cg = 0; cg < 8; cg++) {
      const int lcol = cg * 16 + ln;
      const float fgc = sFg[lcol];
      bs8 b0 = *(const bs8*)&sZf[lcol * 68 + quad * 8];
      bs8 b1 = *(const bs8*)&sZf[lcol * 68 + 32 + quad * 8];
      bs8 bc0 = *(const bs8*)&sZc[lcol * 132 + quad * 8];
      bs8 bc1 = *(const bs8*)&sZc[lcol * 132 + 32 + quad * 8];
      bs8 bc2 = *(const bs8*)&sZc[lcol * 132 + 64 + quad * 8];
      bs8 bc3 = *(const bs8*)&sZc[lcol * 132 + 96 + quad * 8];
#pragma unroll
      for (int rs = 0; rs < 2; rs++) {
        f4 cf = {0.f, 0.f, 0.f, 0.f};
        cf = MFMA_BF16(afg[rs][0], b0, cf);
        cf = MFMA_BF16(afg[rs][1], b1, cf);
#pragma unroll
        for (int r = 0; r < 4; r++) {
          float e = EXP2F(cf[r]);
          dacc[rs][r] += e;
          nacc[rs][r] = fmaf(fgc, e, nacc[rs][r]);
        }
        f4 cs = {0.f, 0.f, 0.f, 0.f};
        cs = MFMA_BF16(acl[rs][0], bc0, cs);
        cs = MFMA_BF16(acl[rs][1], bc1, cs);
        cs = MFMA_BF16(acl[rs][2], bc2, cs);
        cs = MFMA_BF16(acl[rs][3], bc3, cs);
#pragma unroll
        for (int r = 0; r < 4; r++) sacc[rs][r] += EXP2F(cs[r]);
      }
    }
  }

#pragma unroll
  for (int rs = 0; rs < 2; rs++)
#pragma unroll
    for (int r = 0; r < 4; r++) {
      float d = dacc[rs][r], n = nacc[rs][r], s = sacc[rs][r];
#pragma unroll
      for (int off = 1; off < 16; off <<= 1) {
        d += __shfl_xor(d, off, 64);
        n += __shfl_xor(n, off, 64);
        s += __shfl_xor(s, off, 64);
      }
      if (ln == 0) {
        int row = rbase + rs * 16 + quad * 4 + r;
        atomicAdd(&rowD[row], d);
        atomicAdd(&rowN[row], n);
        atomicAdd(&rowS[row], s);
      }
    }
}

// ---------------- per-row losses (scaled-space corrections, verified) -------
__global__ void __launch_bounds__(256) finalize_kernel(
    const unsigned short* __restrict__ Zf, const unsigned short* __restrict__ Zc,
    const int* __restrict__ labels, const float* __restrict__ ious,
    const float* __restrict__ rowD, const float* __restrict__ rowN,
    const float* __restrict__ rowS, const float* __restrict__ Scls,
    const int* __restrict__ hist, const int* __restrict__ nfg,
    float* __restrict__ scal) {
  __shared__ float red[4][4];
  const int t = threadIdx.x, w = t >> 6, lane = t & 63;
  float aw0 = 0.f, al0 = 0.f, aw1 = 0.f, al1 = 0.f;
  const int NFG = *nfg;
  for (int it = 0; it < 16; it++) {
    const int i = it * 512 + blockIdx.x * 4 + w;
    const int lab = labels[i];
    if (lab > 0 && lab < 32) {
      const float iou = ious[i];
      const float iw = (iou > 0.5f) ? iou : 0.f;
      float dot = 0.f, ssq = 0.f;
#pragma unroll
      for (int p = 0; p < 2; p++) {
        const int k = lane + p * 64;
        const float z = bf2f(Zc[(size_t)i * 128 + k]);
        dot = fmaf(z, Scls[lab * 128 + k], dot);
        ssq = fmaf(z, z, ssq);
      }
      float zf = bf2f(Zf[(size_t)i * 64 + lane]);
      float ssqf = zf * zf;
#pragma unroll
      for (int off = 1; off < 64; off <<= 1) {
        dot += __shfl_xor(dot, off, 64);
        ssq += __shfl_xor(ssq, off, 64);
        ssqf += __shfl_xor(ssqf, off, 64);
      }
      if (lane == 0) {
        const float ef = EXP2F(ssqf);
        if (NFG - 1 > 0) {
          const float D = rowD[i] - ef;
          const float Nn = rowN[i] - ef;
          const float loss = logf(D + 2e-8f) - logf(Nn + 1e-8f);
          aw0 += iw;
          al0 += iw * loss;
        }
        const int npc = hist[lab];
        if (npc > 0) {
          const float S = rowS[i] - EXP2F(ssq);
          const float logden = logf(S);
          const float slp = (dot - ssq) * LN2F - (float)(npc - 1) * logden - 1e9f;
          aw1 += iw;
          al1 += iw * (-slp / ((float)npc + 1e-8f));
        }
      }
    }
  }
  if (lane == 0) { red[w][0] = aw0; red[w][1] = al0; red[w][2] = aw1; red[w][3] = al1; }
  __syncthreads();
  if (t < 4) atomicAdd(&scal[t], red[0][t] + red[1][t] + red[2][t] + red[3][t]);
}

__global__ void writeout_kernel(const float* __restrict__ scal, float* __restrict__ out) {
  if (threadIdx.x == 0) {
    out[0] = scal[1] / (scal[0] + 1e-8f);
    out[1] = scal[3] / (scal[2] + 1e-8f);
  }
}

// ---------------- launch ----------------
extern "C" void kernel_launch(void* const* d_in, const int* in_sizes, int n_in,
                              void* d_out, int out_size, void* d_ws, size_t ws_size,
                              hipStream_t stream) {
  (void)in_sizes; (void)n_in; (void)out_size;
  const float* roi    = (const float*)d_in[0];
  const int*   labels = (const int*)d_in[1];
  const float* ious   = (const float*)d_in[2];
  const float* fgw1   = (const float*)d_in[3];
  const float* fgb1   = (const float*)d_in[4];
  const float* fgw2   = (const float*)d_in[5];
  const float* fgb2   = (const float*)d_in[6];
  const float* clsw1  = (const float*)d_in[7];
  const float* clsb1  = (const float*)d_in[8];
  const float* clsw2  = (const float*)d_in[9];
  const float* clsb2  = (const float*)d_in[10];

  char* ws = (char*)d_ws;
  unsigned short* W1T  = (unsigned short*)(ws + O_W1T);
  unsigned short* W2Tf = (unsigned short*)(ws + O_W2TF);
  unsigned short* W2Tc = (unsigned short*)(ws + O_W2TC);
  unsigned short* Hb   = (unsigned short*)(ws + O_H);
  unsigned short* Zf   = (unsigned short*)(ws + O_ZF);
  unsigned short* Zc   = (unsigned short*)(ws + O_ZC);
  unsigned short* Xb   = (unsigned short*)(ws + O_XB);
  float* Scls = (float*)(ws + O_SCLS);
  float* rowD = (float*)(ws + O_ROWD);
  float* rowN = (float*)(ws + O_ROWN);
  float* rowS = (float*)(ws + O_ROWS);
  float* scal = (float*)(ws + O_SCAL);
  int* hist = (int*)(ws + O_HIST);
  int* nfg  = (int*)(ws + O_NFG);
  float* out = (float*)d_out;

  const bool useXb = ws_size >= WS_NEED_XB;
  const int prepBlocks = useXb ? 4350 : 254;

  hipLaunchKernelGGL(prep_kernel, dim3(prepBlocks), dim3(256), 0, stream,
                     roi, labels, fgw1, clsw1, fgw2, clsw2,
                     W1T, W2Tf, W2Tc, (float*)(ws + O_SCLS), hist, nfg, Xb);
  if (useXb) {
    hipLaunchKernelGGL(gemm1x_kernel, dim3(64, 8), dim3(256), 0, stream,
                       Xb, W1T, fgb1, clsb1, Hb);
  } else {
    hipLaunchKernelGGL(gemm1f_kernel, dim3(64, 8), dim3(256), 0, stream,
                       roi, W1T, fgb1, clsb1, Hb);
  }
  hipLaunchKernelGGL(gemm2_kernel, dim3(512), dim3(256), 0, stream,
                     Hb, W2Tf, W2Tc, fgb2, clsb2, Zf, Zc);
  hipLaunchKernelGGL(scls_kernel, dim3(20, 64), dim3(128), 0, stream, Zc, labels, Scls);
  hipLaunchKernelGGL(sim_kernel, dim3(64, 16), dim3(256), 0, stream,
                     Zf, Zc, labels, rowD, rowN, rowS);
  hipLaunchKernelGGL(finalize_kernel, dim3(128), dim3(256), 0, stream,
                     Zf, Zc, labels, ious, rowD, rowN, rowS, Scls, hist, nfg, scal);
  hipLaunchKernelGGL(writeout_kernel, dim3(1), dim3(64), 0, stream, scal, out);
}